// Round 9
// baseline (259.558 us; speedup 1.0000x reference)
//
#include <hip/hip_runtime.h>
#include <hip/hip_bf16.h>
#include <stdint.h>

// Problem: B=8, T=4096, C=1024, D=128 single-head causal attention, fp32 in/out.
// Pipeline: prep_w ; qkv_gemm (fused, x read once, reg-rotated prefetch) ;
// attn_fwd (flash attention, LDS-staged double-buffered K/V via global_load_lds,
// XOR-swizzled). R8: 512 blocks, one qt per block -> 2 blocks/CU (8 waves/CU,
// 2/SIMD). Pairing qt(bid) + qt(bid+256) = 63 exploits round-robin XCD dispatch
// (bid%8=XCD, m09) so each CU slot-pair gets constant causal work.

typedef __attribute__((ext_vector_type(8))) short short8;   // 8 bf16 (4 VGPRs)
typedef __attribute__((ext_vector_type(4))) float f32x4;
typedef __attribute__((ext_vector_type(4))) unsigned short u16x4;

#define NB 8
#define NT 4096
#define NC 1024
#define ND 128

__device__ __forceinline__ unsigned short f2bf(float f) {
    union { float f; uint32_t u; } v; v.f = f;
    uint32_t u = v.u;
    return (unsigned short)((u + 0x7FFFu + ((u >> 16) & 1u)) >> 16);  // RNE
}

// ---------------- W -> bf16, transposed: Wbt[w][n][k] = W_w[k][n] ----------------
__global__ void prep_w(const float* __restrict__ Wq, const float* __restrict__ Wk,
                       const float* __restrict__ Wv, unsigned short* __restrict__ Wbt) {
    int idx = blockIdx.x * 256 + threadIdx.x;          // 0 .. 3*128*1024-1
    int w = idx >> 17;                                  // 131072 per matrix
    int rem = idx & 131071;
    int n = rem >> 10;
    int k = rem & 1023;
    const float* W = (w == 0) ? Wq : (w == 1) ? Wk : Wv;
    Wbt[idx] = f2bf(W[k * ND + n]);
}

// ---------------- fused QKV projection: x[32768][1024] @ {Wq,Wk,Wv} ----------------
// grid 512: blockIdx.x = 64-row M-tile. x read once; next x-tile prefetched to regs
// while MFMA runs (hides HBM latency).
__global__ __launch_bounds__(256, 2)
void qkv_gemm(const float* __restrict__ x, const unsigned short* __restrict__ Wbt,
              unsigned short* __restrict__ Qo, unsigned short* __restrict__ Ko,
              unsigned short* __restrict__ Vto) {
    __shared__ __align__(16) unsigned short xl[64][40];   // 32 + 8 pad (bf16)
    const int mt = blockIdx.x;
    const int tid = threadIdx.x;
    const int lane = tid & 63;
    const int w = tid >> 6;
    const int wr = w >> 1, wc = w & 1;
    const int l15 = lane & 15, lg = lane >> 4;
    const int m0 = mt * 64;
    const int srow = tid >> 3, scol = (tid & 7) * 4;

    f32x4 acc[3][2][4];
#pragma unroll
    for (int nt = 0; nt < 3; ++nt)
#pragma unroll
        for (int mi = 0; mi < 2; ++mi)
#pragma unroll
            for (int ni = 0; ni < 4; ++ni) acc[nt][mi][ni] = (f32x4)0.0f;

    const float* xp0 = &x[(size_t)(m0 + srow) * NC + scol];
    const float* xp1 = &x[(size_t)(m0 + srow + 32) * NC + scol];

    f32x4 vc0 = *reinterpret_cast<const f32x4*>(xp0);
    f32x4 vc1 = *reinterpret_cast<const f32x4*>(xp1);

    for (int ks = 0; ks < 32; ++ks) {
        const int k0 = ks * 32;
        u16x4 b0, b1;
#pragma unroll
        for (int e = 0; e < 4; ++e) { b0[e] = f2bf(vc0[e]); b1[e] = f2bf(vc1[e]); }
        *reinterpret_cast<u16x4*>(&xl[srow][scol]) = b0;
        *reinterpret_cast<u16x4*>(&xl[srow + 32][scol]) = b1;
        __syncthreads();
        f32x4 vn0 = (f32x4)0.0f, vn1 = (f32x4)0.0f;
        if (ks < 31) {                      // prefetch next x tile under the MFMAs
            vn0 = *reinterpret_cast<const f32x4*>(xp0 + k0 + 32);
            vn1 = *reinterpret_cast<const f32x4*>(xp1 + k0 + 32);
        }
        short8 a0 = *reinterpret_cast<const short8*>(&xl[wr * 32 + l15][lg * 8]);
        short8 a1 = *reinterpret_cast<const short8*>(&xl[wr * 32 + 16 + l15][lg * 8]);
#pragma unroll
        for (int nt = 0; nt < 3; ++nt) {
            const unsigned short* Wn = Wbt + (size_t)nt * (ND * NC);
#pragma unroll
            for (int ni = 0; ni < 4; ++ni) {
                short8 bb = *reinterpret_cast<const short8*>(
                    &Wn[(size_t)(wc * 64 + ni * 16 + l15) * NC + k0 + lg * 8]);
                acc[nt][0][ni] = __builtin_amdgcn_mfma_f32_16x16x32_bf16(
                    a0, bb, acc[nt][0][ni], 0, 0, 0);
                acc[nt][1][ni] = __builtin_amdgcn_mfma_f32_16x16x32_bf16(
                    a1, bb, acc[nt][1][ni], 0, 0, 0);
            }
        }
        __syncthreads();
        vc0 = vn0; vc1 = vn1;
    }
    // epilogue: C/D layout col=lane&15, row=(lane>>4)*4+reg
#pragma unroll
    for (int nt = 0; nt < 3; ++nt)
#pragma unroll
        for (int mi = 0; mi < 2; ++mi)
#pragma unroll
            for (int ni = 0; ni < 4; ++ni)
#pragma unroll
                for (int r = 0; r < 4; ++r) {
                    int row = m0 + wr * 32 + mi * 16 + lg * 4 + r;
                    int col = wc * 64 + ni * 16 + l15;
                    unsigned short bv = f2bf(acc[nt][mi][ni][r]);
                    if (nt == 0) Qo[(size_t)row * ND + col] = bv;
                    else if (nt == 1) Ko[(size_t)row * ND + col] = bv;
                    else {
                        int bb2 = row >> 12, t = row & 4095;
                        Vto[((size_t)(bb2 * ND + col)) * NT + t] = bv;
                    }
                }
}

// ---------------- flash attention, causal, LDS-staged double-buffered K/V ----------------
// 512 blocks x 256 threads; block -> (batch b = bid&7, idx = bid>>3 in [0,64)).
// qt = idx<32 ? idx : 95-idx  ->  qt(bid)+qt(bid+256) = 63: with round-robin
// dispatch the two blocks sharing a CU have constant total work (65 tiles).
// 4 waves each own 16 q rows end-to-end (no merge, no spill). K/V tiles staged
// via global_load_lds (16B async) into double-buffered LDS; XOR swizzle
// byte^=((row&7)<<4) applied on the GLOBAL source and on the ds_read side.
__global__ __launch_bounds__(256, 2)
void attn_fwd(const unsigned short* __restrict__ Q, const unsigned short* __restrict__ K,
              const unsigned short* __restrict__ Vt, float* __restrict__ out) {
    __shared__ __align__(16) unsigned short Kl[2][64 * 128];   // [kv 64][d 128] bf16, swizzled
    __shared__ __align__(16) unsigned short Vl[2][128 * 64];   // [d 128][s 64] bf16, swizzled
    __shared__ __align__(16) unsigned short plds[4][16][72];   // per-wave P buffer

    const int bid = blockIdx.x;
    const int idx = bid >> 3, b = bid & 7;
    const int qt = (idx < 32) ? idx : (95 - idx);
    const int tid = threadIdx.x;
    const int w = tid >> 6, lane = tid & 63;
    const int l15 = lane & 15, lg = lane >> 4;

    const float sc = 0.08838834764831845f;     // 1/sqrt(128)
    const float L2E = 1.4426950408889634f;

    const unsigned short* Kbase = &K[(size_t)b * NT * ND];
    const unsigned short* Vbase = &Vt[(size_t)b * ND * NT];

    // stage one 64-wide KV tile (K: 64x256B, V: 128x128B) into buffer `buf`
    auto stage = [&](int buf, int s0) {
#pragma unroll
        for (int r = 0; r < 4; ++r) {          // K tile: 4 rounds x 4KB
            int off = r * 4096 + w * 1024 + lane * 16;
            int row = off >> 8;
            int gcol = (off & 255) ^ ((row & 7) << 4);
            const unsigned short* src = Kbase + (size_t)(s0 + row) * ND + (gcol >> 1);
            __builtin_amdgcn_global_load_lds(
                (const __attribute__((address_space(1))) void*)src,
                (__attribute__((address_space(3))) void*)&Kl[buf][(r * 4096 + w * 1024) >> 1],
                16, 0, 0);
        }
#pragma unroll
        for (int r = 0; r < 4; ++r) {          // V tile: 4 rounds x 4KB
            int off = r * 4096 + w * 1024 + lane * 16;
            int row = off >> 7;
            int gcol = (off & 127) ^ ((row & 7) << 4);
            const unsigned short* src = Vbase + (size_t)row * NT + s0 + (gcol >> 1);
            __builtin_amdgcn_global_load_lds(
                (const __attribute__((address_space(1))) void*)src,
                (__attribute__((address_space(3))) void*)&Vl[buf][(r * 4096 + w * 1024) >> 1],
                16, 0, 0);
        }
    };

    const int qb0 = qt * 64;
    const int qw0 = qb0 + w * 16;
    const int ntiles = qt + 1;

    // Q fragments (hoisted): A-frag lane l holds Q[m=l&15][k-chunk per l>>4]
    short8 qf[4];
    const size_t qbase = ((size_t)b * NT + qw0 + l15) * ND;
#pragma unroll
    for (int c = 0; c < 4; ++c)
        qf[c] = *reinterpret_cast<const short8*>(&Q[qbase + c * 32 + lg * 8]);

    f32x4 o[8];
#pragma unroll
    for (int jn = 0; jn < 8; ++jn) o[jn] = (f32x4)0.0f;
    float mrow[4], lsum[4];
#pragma unroll
    for (int r = 0; r < 4; ++r) { mrow[r] = -1e30f; lsum[r] = 0.0f; }

    stage(0, 0);
    __syncthreads();                       // drains vmcnt: tile 0 ready
    int cur = 0;

    for (int t = 0; t < ntiles; ++t) {
        const int s0 = t * 64;
        if (t + 1 < ntiles) stage(cur ^ 1, s0 + 64);   // async prefetch next tile

        // ---- S = Q K^T from Kl[cur] ----
        const unsigned short* KlC = &Kl[cur][0];
        f32x4 s[4];
#pragma unroll
        for (int j = 0; j < 4; ++j) s[j] = (f32x4)0.0f;
        __builtin_amdgcn_s_setprio(1);
#pragma unroll
        for (int j = 0; j < 4; ++j) {
            const int row = j * 16 + l15;
            const int cb = (row & 7) << 4;
#pragma unroll
            for (int c = 0; c < 4; ++c) {
                short8 kf = *reinterpret_cast<const short8*>(
                    &KlC[row * 128 + (((c * 64 + lg * 16) ^ cb) >> 1)]);
                s[j] = __builtin_amdgcn_mfma_f32_16x16x32_bf16(qf[c], kf, s[j], 0, 0, 0);
            }
        }
        __builtin_amdgcn_s_setprio(0);

        // ---- prefetch V half (jn=0..3) from LDS: hides under softmax ----
        const unsigned short* VlC = &Vl[cur][0];
        short8 vf0[8];
#pragma unroll
        for (int jn = 0; jn < 4; ++jn) {
            const int row = jn * 16 + l15;
            const int cb = (row & 7) << 4;
#pragma unroll
            for (int kc = 0; kc < 2; ++kc)
                vf0[jn * 2 + kc] = *reinterpret_cast<const short8*>(
                    &VlC[row * 64 + (((kc * 64 + lg * 16) ^ cb) >> 1)]);
        }

        // ---- softmax (online) ----
        const bool diag = (s0 + 64 > qw0);
        float tmax[4];
#pragma unroll
        for (int r = 0; r < 4; ++r) tmax[r] = -1e30f;
#pragma unroll
        for (int j = 0; j < 4; ++j)
#pragma unroll
            for (int r = 0; r < 4; ++r) {
                float sv = s[j][r] * sc;
                if (diag) {
                    int qrow = qw0 + lg * 4 + r;
                    int scol = s0 + j * 16 + l15;
                    if (scol > qrow) sv = -1e30f;
                }
                s[j][r] = sv;
                tmax[r] = fmaxf(tmax[r], sv);
            }
#pragma unroll
        for (int r = 0; r < 4; ++r) {
#pragma unroll
            for (int off = 1; off < 16; off <<= 1)
                tmax[r] = fmaxf(tmax[r], __shfl_xor(tmax[r], off, 64));
        }
        float alpha[4], psum[4];
#pragma unroll
        for (int r = 0; r < 4; ++r) {
            float mn = fmaxf(mrow[r], tmax[r]);
            alpha[r] = exp2f((mrow[r] - mn) * L2E);
            mrow[r] = mn;
            psum[r] = 0.0f;
        }
#pragma unroll
        for (int j = 0; j < 4; ++j)
#pragma unroll
            for (int r = 0; r < 4; ++r) {
                float pv = exp2f((s[j][r] - mrow[r]) * L2E);
                s[j][r] = pv;
                psum[r] += pv;
            }
#pragma unroll
        for (int r = 0; r < 4; ++r) {
#pragma unroll
            for (int off = 1; off < 16; off <<= 1)
                psum[r] += __shfl_xor(psum[r], off, 64);
            lsum[r] = lsum[r] * alpha[r] + psum[r];
        }
        // rescale O
#pragma unroll
        for (int jn = 0; jn < 8; ++jn)
#pragma unroll
            for (int r = 0; r < 4; ++r) o[jn][r] *= alpha[r];

        // ---- P -> LDS (D-layout coords), reload as A-frags ----
#pragma unroll
        for (int j = 0; j < 4; ++j)
#pragma unroll
            for (int r = 0; r < 4; ++r)
                plds[w][lg * 4 + r][j * 16 + l15] = f2bf(s[j][r]);
        asm volatile("s_waitcnt lgkmcnt(0)" ::: "memory");
        short8 pa[2];
#pragma unroll
        for (int kc = 0; kc < 2; ++kc)
            pa[kc] = *reinterpret_cast<const short8*>(&plds[w][l15][kc * 32 + lg * 8]);

        // ---- O += P V : half 0 from prefetched regs, half 1 from LDS ----
        __builtin_amdgcn_s_setprio(1);
#pragma unroll
        for (int jn = 0; jn < 4; ++jn)
#pragma unroll
            for (int kc = 0; kc < 2; ++kc)
                o[jn] = __builtin_amdgcn_mfma_f32_16x16x32_bf16(
                    pa[kc], vf0[jn * 2 + kc], o[jn], 0, 0, 0);
#pragma unroll
        for (int jn = 4; jn < 8; ++jn) {
            const int row = jn * 16 + l15;
            const int cb = (row & 7) << 4;
#pragma unroll
            for (int kc = 0; kc < 2; ++kc) {
                short8 vf = *reinterpret_cast<const short8*>(
                    &VlC[row * 64 + (((kc * 64 + lg * 16) ^ cb) >> 1)]);
                o[jn] = __builtin_amdgcn_mfma_f32_16x16x32_bf16(pa[kc], vf, o[jn], 0, 0, 0);
            }
        }
        __builtin_amdgcn_s_setprio(0);

        __syncthreads();                   // prefetch done (vmcnt) + reads drained
        cur ^= 1;
    }

    // ---- epilogue: each wave writes its own 16 rows ----
    float il[4];
#pragma unroll
    for (int r = 0; r < 4; ++r) il[r] = 1.0f / lsum[r];
#pragma unroll
    for (int jn = 0; jn < 8; ++jn)
#pragma unroll
        for (int r = 0; r < 4; ++r)
            out[((size_t)b * NT + qw0 + lg * 4 + r) * ND + jn * 16 + l15] =
                o[jn][r] * il[r];
}

extern "C" void kernel_launch(void* const* d_in, const int* in_sizes, int n_in,
                              void* d_out, int out_size, void* d_ws, size_t ws_size,
                              hipStream_t stream) {
    const float* x  = (const float*)d_in[0];
    const float* Wq = (const float*)d_in[1];
    const float* Wk = (const float*)d_in[2];
    const float* Wv = (const float*)d_in[3];
    float* out = (float*)d_out;

    unsigned short* ws  = (unsigned short*)d_ws;
    unsigned short* Wbt = ws;                               // 3*128*1024
    unsigned short* Qb  = Wbt + 3 * ND * NC;                // 8*4096*128
    unsigned short* Kb  = Qb + (size_t)NB * NT * ND;
    unsigned short* Vtb = Kb + (size_t)NB * NT * ND;        // transposed [B][D][T]

    prep_w<<<1536, 256, 0, stream>>>(Wq, Wk, Wv, Wbt);
    qkv_gemm<<<512, 256, 0, stream>>>(x, Wbt, Qb, Kb, Vtb);
    attn_fwd<<<512, 256, 0, stream>>>(Qb, Kb, Vtb, out);
}

// Round 10
// 216.768 us; speedup vs baseline: 1.1974x; 1.1974x over previous
//
#include <hip/hip_runtime.h>
#include <hip/hip_bf16.h>
#include <stdint.h>

// Problem: B=8, T=4096, C=1024, D=128 single-head causal attention, fp32 in/out.
// Pipeline: prep_w ; qkv_gemm (fused, x read once) ; attn_fwd.
// R9: 8-wave (512-thread) blocks, split-KV x2 across wave halves (group g takes
// KV tiles t==g mod 2), per-group double-buffered LDS K/V (146KB, 1 block/CU by
// design -> 8 waves = 2/SIMD), sequential halves (qt=p, 63-p) -> exactly 33
// iterations per block (uniform, no dispatch assumptions). Group merge via LDS
// aliased onto the dead K region.

typedef __attribute__((ext_vector_type(8))) short short8;   // 8 bf16 (4 VGPRs)
typedef __attribute__((ext_vector_type(4))) float f32x4;
typedef __attribute__((ext_vector_type(4))) unsigned short u16x4;

#define NB 8
#define NT 4096
#define NC 1024
#define ND 128

__device__ __forceinline__ unsigned short f2bf(float f) {
    union { float f; uint32_t u; } v; v.f = f;
    uint32_t u = v.u;
    return (unsigned short)((u + 0x7FFFu + ((u >> 16) & 1u)) >> 16);  // RNE
}

// ---------------- W -> bf16, transposed: Wbt[w][n][k] = W_w[k][n] ----------------
__global__ void prep_w(const float* __restrict__ Wq, const float* __restrict__ Wk,
                       const float* __restrict__ Wv, unsigned short* __restrict__ Wbt) {
    int idx = blockIdx.x * 256 + threadIdx.x;          // 0 .. 3*128*1024-1
    int w = idx >> 17;                                  // 131072 per matrix
    int rem = idx & 131071;
    int n = rem >> 10;
    int k = rem & 1023;
    const float* W = (w == 0) ? Wq : (w == 1) ? Wk : Wv;
    Wbt[idx] = f2bf(W[k * ND + n]);
}

// ---------------- fused QKV projection: x[32768][1024] @ {Wq,Wk,Wv} ----------------
__global__ __launch_bounds__(256, 2)
void qkv_gemm(const float* __restrict__ x, const unsigned short* __restrict__ Wbt,
              unsigned short* __restrict__ Qo, unsigned short* __restrict__ Ko,
              unsigned short* __restrict__ Vto) {
    __shared__ __align__(16) unsigned short xl[64][40];   // 32 + 8 pad (bf16)
    const int mt = blockIdx.x;
    const int tid = threadIdx.x;
    const int lane = tid & 63;
    const int w = tid >> 6;
    const int wr = w >> 1, wc = w & 1;
    const int l15 = lane & 15, lg = lane >> 4;
    const int m0 = mt * 64;
    const int srow = tid >> 3, scol = (tid & 7) * 4;

    f32x4 acc[3][2][4];
#pragma unroll
    for (int nt = 0; nt < 3; ++nt)
#pragma unroll
        for (int mi = 0; mi < 2; ++mi)
#pragma unroll
            for (int ni = 0; ni < 4; ++ni) acc[nt][mi][ni] = (f32x4)0.0f;

    const float* xp0 = &x[(size_t)(m0 + srow) * NC + scol];
    const float* xp1 = &x[(size_t)(m0 + srow + 32) * NC + scol];

    f32x4 vc0 = *reinterpret_cast<const f32x4*>(xp0);
    f32x4 vc1 = *reinterpret_cast<const f32x4*>(xp1);

    for (int ks = 0; ks < 32; ++ks) {
        const int k0 = ks * 32;
        u16x4 b0, b1;
#pragma unroll
        for (int e = 0; e < 4; ++e) { b0[e] = f2bf(vc0[e]); b1[e] = f2bf(vc1[e]); }
        *reinterpret_cast<u16x4*>(&xl[srow][scol]) = b0;
        *reinterpret_cast<u16x4*>(&xl[srow + 32][scol]) = b1;
        __syncthreads();
        f32x4 vn0 = (f32x4)0.0f, vn1 = (f32x4)0.0f;
        if (ks < 31) {                      // prefetch next x tile under the MFMAs
            vn0 = *reinterpret_cast<const f32x4*>(xp0 + k0 + 32);
            vn1 = *reinterpret_cast<const f32x4*>(xp1 + k0 + 32);
        }
        short8 a0 = *reinterpret_cast<const short8*>(&xl[wr * 32 + l15][lg * 8]);
        short8 a1 = *reinterpret_cast<const short8*>(&xl[wr * 32 + 16 + l15][lg * 8]);
#pragma unroll
        for (int nt = 0; nt < 3; ++nt) {
            const unsigned short* Wn = Wbt + (size_t)nt * (ND * NC);
#pragma unroll
            for (int ni = 0; ni < 4; ++ni) {
                short8 bb = *reinterpret_cast<const short8*>(
                    &Wn[(size_t)(wc * 64 + ni * 16 + l15) * NC + k0 + lg * 8]);
                acc[nt][0][ni] = __builtin_amdgcn_mfma_f32_16x16x32_bf16(
                    a0, bb, acc[nt][0][ni], 0, 0, 0);
                acc[nt][1][ni] = __builtin_amdgcn_mfma_f32_16x16x32_bf16(
                    a1, bb, acc[nt][1][ni], 0, 0, 0);
            }
        }
        __syncthreads();
        vc0 = vn0; vc1 = vn1;
    }
#pragma unroll
    for (int nt = 0; nt < 3; ++nt)
#pragma unroll
        for (int mi = 0; mi < 2; ++mi)
#pragma unroll
            for (int ni = 0; ni < 4; ++ni)
#pragma unroll
                for (int r = 0; r < 4; ++r) {
                    int row = m0 + wr * 32 + mi * 16 + lg * 4 + r;
                    int col = wc * 64 + ni * 16 + l15;
                    unsigned short bv = f2bf(acc[nt][mi][ni][r]);
                    if (nt == 0) Qo[(size_t)row * ND + col] = bv;
                    else if (nt == 1) Ko[(size_t)row * ND + col] = bv;
                    else {
                        int bb2 = row >> 12, t = row & 4095;
                        Vto[((size_t)(bb2 * ND + col)) * NT + t] = bv;
                    }
                }
}

// ---------------- flash attention, causal, 8-wave split-KV x2 ----------------
// 256 blocks x 512 threads; block -> (b = bid&7, p = bid>>3 in [0,32)).
// Sequential halves qt = p then 63-p; per half, group g = w>>2 handles KV tiles
// t == g (mod 2) with its OWN double-buffered K/V LDS. Exactly 33 iterations
// per block. Group-1 partials merged into group-0 via LDS aliased on dead K region.
__global__ __launch_bounds__(512, 2)
void attn_fwd(const unsigned short* __restrict__ Q, const unsigned short* __restrict__ K,
              const unsigned short* __restrict__ Vt, float* __restrict__ out) {
    // [0,65536)        K: group g at g*32768, buf at +buf*16384   (64x128 bf16, swizzled)
    // [65536,131072)   V: group g at 65536+g*32768, buf +buf*16384 (128x64 bf16, swizzled)
    // [131072,149504)  plds: wave w at +w*2304 (16x72 bf16)
    // merge (after loop): O pairs at [0,32768), m/l at [32768,33280)
    __shared__ __align__(16) char smem[149504];

    const int bid = blockIdx.x;
    const int p = bid >> 3, b = bid & 7;
    const int tid = threadIdx.x;
    const int w = tid >> 6, lane = tid & 63;
    const int l15 = lane & 15, lg = lane >> 4;
    const int g = w >> 2, wq = w & 3;

    const float sc = 0.08838834764831845f;     // 1/sqrt(128)
    const float L2E = 1.4426950408889634f;

    unsigned short* Kg = (unsigned short*)(smem + g * 32768);
    unsigned short* Vg = (unsigned short*)(smem + 65536 + g * 32768);
    unsigned short* pw = (unsigned short*)(smem + 131072 + w * 2304);
    float* mOp = (float*)(smem) + wq * 2048;            // 16x128 f32 per pair
    float* mml = (float*)(smem + 32768) + wq * 32;      // [2][16] per pair

    const unsigned short* Kbase = &K[(size_t)b * NT * ND];
    const unsigned short* Vbase = &Vt[(size_t)b * ND * NT];

    // stage this group's 64-wide KV tile into buffer `buf` (wave covers 4KB of each)
    auto stage = [&](int buf, int s0) {
#pragma unroll
        for (int r = 0; r < 4; ++r) {          // K tile: 64 rows x 256B
            int off = r * 4096 + wq * 1024 + lane * 16;
            int row = off >> 8;
            int gcol = (off & 255) ^ ((row & 7) << 4);
            const unsigned short* src = Kbase + (size_t)(s0 + row) * ND + (gcol >> 1);
            __builtin_amdgcn_global_load_lds(
                (const __attribute__((address_space(1))) void*)src,
                (__attribute__((address_space(3))) void*)(Kg + ((buf * 16384 + r * 4096 + wq * 1024) >> 1)),
                16, 0, 0);
        }
#pragma unroll
        for (int r = 0; r < 4; ++r) {          // V tile: 128 rows x 128B
            int off = r * 4096 + wq * 1024 + lane * 16;
            int row = off >> 7;
            int gcol = (off & 127) ^ ((row & 7) << 4);
            const unsigned short* src = Vbase + (size_t)row * NT + s0 + (gcol >> 1);
            __builtin_amdgcn_global_load_lds(
                (const __attribute__((address_space(1))) void*)src,
                (__attribute__((address_space(3))) void*)(Vg + ((buf * 16384 + r * 4096 + wq * 1024) >> 1)),
                16, 0, 0);
        }
    };

    for (int half = 0; half < 2; ++half) {
        const int qt = half ? (63 - p) : p;
        const int qb0 = qt * 64;
        const int qw0 = qb0 + wq * 16;
        const int niter = (qt + 2) >> 1;       // ceil((qt+1)/2)

        // Q fragments: A-frag lane l holds Q[m=l&15][k-chunk per l>>4]
        short8 qf[4];
        const size_t qbase = ((size_t)b * NT + qw0 + l15) * ND;
#pragma unroll
        for (int c = 0; c < 4; ++c)
            qf[c] = *reinterpret_cast<const short8*>(&Q[qbase + c * 32 + lg * 8]);

        f32x4 o[8];
#pragma unroll
        for (int jn = 0; jn < 8; ++jn) o[jn] = (f32x4)0.0f;
        float mrow[4], lsum[4];
#pragma unroll
        for (int r = 0; r < 4; ++r) { mrow[r] = -1e30f; lsum[r] = 0.0f; }

        if (g <= qt) stage(0, g * 64);
        __syncthreads();                       // drains vmcnt: first tiles ready
        int cur = 0;

        for (int i = 0; i < niter; ++i) {
            const int t = 2 * i + g;
            const int s0 = t * 64;
            if (t + 2 <= qt) stage(cur ^ 1, (t + 2) * 64);

            if (t <= qt) {
                // ---- S = Q K^T from Kg[cur] ----
                const unsigned short* KlC = Kg + cur * 8192;
                f32x4 s[4];
#pragma unroll
                for (int j = 0; j < 4; ++j) s[j] = (f32x4)0.0f;
                __builtin_amdgcn_s_setprio(1);
#pragma unroll
                for (int j = 0; j < 4; ++j) {
                    const int row = j * 16 + l15;
                    const int cb = (row & 7) << 4;
#pragma unroll
                    for (int c = 0; c < 4; ++c) {
                        short8 kf = *reinterpret_cast<const short8*>(
                            &KlC[row * 128 + (((c * 64 + lg * 16) ^ cb) >> 1)]);
                        s[j] = __builtin_amdgcn_mfma_f32_16x16x32_bf16(qf[c], kf, s[j], 0, 0, 0);
                    }
                }
                __builtin_amdgcn_s_setprio(0);

                // ---- prefetch V half (jn=0..3) from LDS: hides under softmax ----
                const unsigned short* VlC = Vg + cur * 8192;
                short8 vf0[8];
#pragma unroll
                for (int jn = 0; jn < 4; ++jn) {
                    const int row = jn * 16 + l15;
                    const int cb = (row & 7) << 4;
#pragma unroll
                    for (int kc = 0; kc < 2; ++kc)
                        vf0[jn * 2 + kc] = *reinterpret_cast<const short8*>(
                            &VlC[row * 64 + (((kc * 64 + lg * 16) ^ cb) >> 1)]);
                }

                // ---- softmax (online) ----
                const bool diag = (s0 + 64 > qw0);
                float tmax[4];
#pragma unroll
                for (int r = 0; r < 4; ++r) tmax[r] = -1e30f;
#pragma unroll
                for (int j = 0; j < 4; ++j)
#pragma unroll
                    for (int r = 0; r < 4; ++r) {
                        float sv = s[j][r] * sc;
                        if (diag) {
                            int qrow = qw0 + lg * 4 + r;
                            int scol = s0 + j * 16 + l15;
                            if (scol > qrow) sv = -1e30f;
                        }
                        s[j][r] = sv;
                        tmax[r] = fmaxf(tmax[r], sv);
                    }
#pragma unroll
                for (int r = 0; r < 4; ++r) {
#pragma unroll
                    for (int off = 1; off < 16; off <<= 1)
                        tmax[r] = fmaxf(tmax[r], __shfl_xor(tmax[r], off, 64));
                }
                float alpha[4], psum[4];
#pragma unroll
                for (int r = 0; r < 4; ++r) {
                    float mn = fmaxf(mrow[r], tmax[r]);
                    alpha[r] = exp2f((mrow[r] - mn) * L2E);
                    mrow[r] = mn;
                    psum[r] = 0.0f;
                }
#pragma unroll
                for (int j = 0; j < 4; ++j)
#pragma unroll
                    for (int r = 0; r < 4; ++r) {
                        float pv = exp2f((s[j][r] - mrow[r]) * L2E);
                        s[j][r] = pv;
                        psum[r] += pv;
                    }
#pragma unroll
                for (int r = 0; r < 4; ++r) {
#pragma unroll
                    for (int off = 1; off < 16; off <<= 1)
                        psum[r] += __shfl_xor(psum[r], off, 64);
                    lsum[r] = lsum[r] * alpha[r] + psum[r];
                }
#pragma unroll
                for (int jn = 0; jn < 8; ++jn)
#pragma unroll
                    for (int r = 0; r < 4; ++r) o[jn][r] *= alpha[r];

                // ---- P -> LDS (D-layout coords), reload as A-frags ----
#pragma unroll
                for (int j = 0; j < 4; ++j)
#pragma unroll
                    for (int r = 0; r < 4; ++r)
                        pw[(lg * 4 + r) * 72 + j * 16 + l15] = f2bf(s[j][r]);
                asm volatile("s_waitcnt lgkmcnt(0)" ::: "memory");
                short8 pa[2];
#pragma unroll
                for (int kc = 0; kc < 2; ++kc)
                    pa[kc] = *reinterpret_cast<const short8*>(&pw[l15 * 72 + kc * 32 + lg * 8]);

                // ---- O += P V ----
                __builtin_amdgcn_s_setprio(1);
#pragma unroll
                for (int jn = 0; jn < 4; ++jn)
#pragma unroll
                    for (int kc = 0; kc < 2; ++kc)
                        o[jn] = __builtin_amdgcn_mfma_f32_16x16x32_bf16(
                            pa[kc], vf0[jn * 2 + kc], o[jn], 0, 0, 0);
#pragma unroll
                for (int jn = 4; jn < 8; ++jn) {
                    const int row = jn * 16 + l15;
                    const int cb = (row & 7) << 4;
#pragma unroll
                    for (int kc = 0; kc < 2; ++kc) {
                        short8 vf = *reinterpret_cast<const short8*>(
                            &VlC[row * 64 + (((kc * 64 + lg * 16) ^ cb) >> 1)]);
                        o[jn] = __builtin_amdgcn_mfma_f32_16x16x32_bf16(pa[kc], vf, o[jn], 0, 0, 0);
                    }
                }
                __builtin_amdgcn_s_setprio(0);
            }

            __syncthreads();                   // prefetch done + reads drained
            cur ^= 1;
        }

        // ---- merge: group1 publishes (m,l,O) via LDS (aliases dead K region) ----
        if (g == 1) {
#pragma unroll
            for (int jn = 0; jn < 8; ++jn)
#pragma unroll
                for (int r = 0; r < 4; ++r)
                    mOp[(lg * 4 + r) * 128 + jn * 16 + l15] = o[jn][r];
            if (l15 == 0) {
#pragma unroll
                for (int r = 0; r < 4; ++r) {
                    mml[lg * 4 + r] = mrow[r];
                    mml[16 + lg * 4 + r] = lsum[r];
                }
            }
        }
        __syncthreads();
        if (g == 0) {
            float e0[4], e1[4], rL[4];
#pragma unroll
            for (int r = 0; r < 4; ++r) {
                int rr = lg * 4 + r;
                float m1 = mml[rr], l1 = mml[16 + rr];
                float M = fmaxf(mrow[r], m1);
                e0[r] = exp2f((mrow[r] - M) * L2E);
                e1[r] = exp2f((m1 - M) * L2E);
                rL[r] = 1.0f / (lsum[r] * e0[r] + l1 * e1[r]);
            }
#pragma unroll
            for (int jn = 0; jn < 8; ++jn)
#pragma unroll
                for (int r = 0; r < 4; ++r) {
                    int rr = lg * 4 + r, cc = jn * 16 + l15;
                    float v = o[jn][r] * e0[r] + mOp[rr * 128 + cc] * e1[r];
                    out[((size_t)b * NT + qw0 + rr) * ND + cc] = v * rL[r];
                }
        }
        __syncthreads();                       // merge reads done before restaging
    }
}

extern "C" void kernel_launch(void* const* d_in, const int* in_sizes, int n_in,
                              void* d_out, int out_size, void* d_ws, size_t ws_size,
                              hipStream_t stream) {
    const float* x  = (const float*)d_in[0];
    const float* Wq = (const float*)d_in[1];
    const float* Wk = (const float*)d_in[2];
    const float* Wv = (const float*)d_in[3];
    float* out = (float*)d_out;

    unsigned short* ws  = (unsigned short*)d_ws;
    unsigned short* Wbt = ws;                               // 3*128*1024
    unsigned short* Qb  = Wbt + 3 * ND * NC;                // 8*4096*128
    unsigned short* Kb  = Qb + (size_t)NB * NT * ND;
    unsigned short* Vtb = Kb + (size_t)NB * NT * ND;        // transposed [B][D][T]

    prep_w<<<1536, 256, 0, stream>>>(Wq, Wk, Wv, Wbt);
    qkv_gemm<<<512, 256, 0, stream>>>(x, Wbt, Qb, Kb, Vtb);
    attn_fwd<<<256, 512, 0, stream>>>(Qb, Kb, Vtb, out);
}

// Round 11
// 158.268 us; speedup vs baseline: 1.6400x; 1.3696x over previous
//
#include <hip/hip_runtime.h>
#include <hip/hip_bf16.h>
#include <stdint.h>

// Problem: B=8, T=4096, C=1024, D=128 single-head causal attention, fp32 in/out.
// Pipeline: prep_w ; qkv_gemm (m97-structure GEMM: 128x128 tile, K-step 64,
// global_load_lds both operands, XOR-swizzled LDS, A kept fp32 in LDS and
// converted at fragment read) ; attn_fwd (8-wave split-KV x2, unchanged from R9).

typedef __attribute__((ext_vector_type(8))) short short8;   // 8 bf16 (4 VGPRs)
typedef __attribute__((ext_vector_type(4))) float f32x4;
typedef __attribute__((ext_vector_type(4))) unsigned short u16x4;

#define NB 8
#define NT 4096
#define NC 1024
#define ND 128

__device__ __forceinline__ unsigned short f2bf(float f) {
    union { float f; uint32_t u; } v; v.f = f;
    uint32_t u = v.u;
    return (unsigned short)((u + 0x7FFFu + ((u >> 16) & 1u)) >> 16);  // RNE
}

// ---------------- W -> bf16, transposed: Wbt[w][n][k] = W_w[k][n] ----------------
__global__ void prep_w(const float* __restrict__ Wq, const float* __restrict__ Wk,
                       const float* __restrict__ Wv, unsigned short* __restrict__ Wbt) {
    int idx = blockIdx.x * 256 + threadIdx.x;          // 0 .. 3*128*1024-1
    int w = idx >> 17;                                  // 131072 per matrix
    int rem = idx & 131071;
    int n = rem >> 10;
    int k = rem & 1023;
    const float* W = (w == 0) ? Wq : (w == 1) ? Wk : Wv;
    Wbt[idx] = f2bf(W[k * ND + n]);
}

// ---------------- QKV projection, m97 structure ----------------
// grid (256, 3): blockIdx.x = 128-row M-tile, blockIdx.y = {Q,K,V}. 768 blocks
// = 3/CU. Single-buffered LDS (48 KB), 2-barrier K-loop, K-step 64.
// A (x tile) staged as RAW FP32 via global_load_lds (pre-swizzled source),
// converted bf16 at fragment read. B (W^T tile) staged bf16 the same way.
__global__ __launch_bounds__(256, 3)
void qkv_gemm(const float* __restrict__ x, const unsigned short* __restrict__ Wbt,
              unsigned short* __restrict__ Qo, unsigned short* __restrict__ Ko,
              unsigned short* __restrict__ Vto) {
    __shared__ __align__(16) float Al[128 * 64];           // 32 KB fp32, swizzled
    __shared__ __align__(16) unsigned short Bl[128 * 64];  // 16 KB bf16, swizzled
    const int mt = blockIdx.x, nt = blockIdx.y;
    const int tid = threadIdx.x;
    const int lane = tid & 63;
    const int w = tid >> 6;
    const int wr = w >> 1, wc = w & 1;
    const int l15 = lane & 15, lg = lane >> 4;
    const int m0 = mt * 128;
    const unsigned short* Wn = Wbt + (size_t)nt * (ND * NC);

    f32x4 acc[4][4];
#pragma unroll
    for (int i = 0; i < 4; ++i)
#pragma unroll
        for (int j = 0; j < 4; ++j) acc[i][j] = (f32x4)0.0f;

    for (int ks = 0; ks < 16; ++ks) {
        const int k0 = ks * 64;
        // ---- stage A: 128 rows x 64 k fp32 (32 KB), linear LDS dest,
        //      inverse-swizzled global source ----
#pragma unroll
        for (int r = 0; r < 8; ++r) {
            int o = r * 4096 + tid * 16;                 // linear byte offset
            int row = o >> 8;                             // 256 B per row
            int colb = (o & 255) ^ ((row & 7) << 4);
            const float* src = x + (size_t)(m0 + row) * NC + k0 + (colb >> 2);
            __builtin_amdgcn_global_load_lds(
                (const __attribute__((address_space(1))) void*)src,
                (__attribute__((address_space(3))) void*)((char*)Al + o), 16, 0, 0);
        }
        // ---- stage B: 128 rows x 64 k bf16 (16 KB) ----
#pragma unroll
        for (int r = 0; r < 4; ++r) {
            int o = r * 4096 + tid * 16;
            int row = o >> 7;                             // 128 B per row
            int colb = (o & 127) ^ ((row & 7) << 4);
            const unsigned short* src = Wn + (size_t)row * NC + k0 + (colb >> 1);
            __builtin_amdgcn_global_load_lds(
                (const __attribute__((address_space(1))) void*)src,
                (__attribute__((address_space(3))) void*)((char*)Bl + o), 16, 0, 0);
        }
        __syncthreads();                                  // drain: tiles ready

        // ---- fragments + MFMA (wave quadrant 64x64, 32 MFMA per K-step) ----
#pragma unroll
        for (int kc = 0; kc < 2; ++kc) {
            short8 a[4], b[4];
#pragma unroll
            for (int mi = 0; mi < 4; ++mi) {
                const int row = wr * 64 + mi * 16 + l15;
                const int cb = (row & 7) << 4;
                const int base = row * 256;
                f32x4 lo = *reinterpret_cast<const f32x4*>(
                    (const char*)Al + base + ((kc * 128 + lg * 32) ^ cb));
                f32x4 hi = *reinterpret_cast<const f32x4*>(
                    (const char*)Al + base + ((kc * 128 + lg * 32 + 16) ^ cb));
                short8 av;
#pragma unroll
                for (int e = 0; e < 4; ++e) {
                    av[e] = (short)f2bf(lo[e]);
                    av[4 + e] = (short)f2bf(hi[e]);
                }
                a[mi] = av;
            }
#pragma unroll
            for (int ni = 0; ni < 4; ++ni) {
                const int row = wc * 64 + ni * 16 + l15;
                const int cb = (row & 7) << 4;
                b[ni] = *reinterpret_cast<const short8*>(
                    (const char*)Bl + row * 128 + ((kc * 64 + lg * 16) ^ cb));
            }
#pragma unroll
            for (int mi = 0; mi < 4; ++mi)
#pragma unroll
                for (int ni = 0; ni < 4; ++ni)
                    acc[mi][ni] = __builtin_amdgcn_mfma_f32_16x16x32_bf16(
                        a[mi], b[ni], acc[mi][ni], 0, 0, 0);
        }
        __syncthreads();                                  // reads done before restage
    }
    // ---- epilogue: C/D layout col=lane&15, row=(lane>>4)*4+reg ----
#pragma unroll
    for (int mi = 0; mi < 4; ++mi)
#pragma unroll
        for (int ni = 0; ni < 4; ++ni)
#pragma unroll
            for (int r = 0; r < 4; ++r) {
                int row = m0 + wr * 64 + mi * 16 + lg * 4 + r;
                int col = wc * 64 + ni * 16 + l15;
                unsigned short bv = f2bf(acc[mi][ni][r]);
                if (nt == 0) Qo[(size_t)row * ND + col] = bv;
                else if (nt == 1) Ko[(size_t)row * ND + col] = bv;
                else {
                    int bb2 = row >> 12, t = row & 4095;
                    Vto[((size_t)(bb2 * ND + col)) * NT + t] = bv;
                }
            }
}

// ---------------- flash attention, causal, 8-wave split-KV x2 (unchanged R9) ----------------
__global__ __launch_bounds__(512, 2)
void attn_fwd(const unsigned short* __restrict__ Q, const unsigned short* __restrict__ K,
              const unsigned short* __restrict__ Vt, float* __restrict__ out) {
    // [0,65536)        K: group g at g*32768, buf at +buf*16384   (64x128 bf16, swizzled)
    // [65536,131072)   V: group g at 65536+g*32768, buf +buf*16384 (128x64 bf16, swizzled)
    // [131072,149504)  plds: wave w at +w*2304 (16x72 bf16)
    // merge (after loop): O pairs at [0,32768), m/l at [32768,33280)
    __shared__ __align__(16) char smem[149504];

    const int bid = blockIdx.x;
    const int p = bid >> 3, b = bid & 7;
    const int tid = threadIdx.x;
    const int w = tid >> 6, lane = tid & 63;
    const int l15 = lane & 15, lg = lane >> 4;
    const int g = w >> 2, wq = w & 3;

    const float sc = 0.08838834764831845f;     // 1/sqrt(128)
    const float L2E = 1.4426950408889634f;

    unsigned short* Kg = (unsigned short*)(smem + g * 32768);
    unsigned short* Vg = (unsigned short*)(smem + 65536 + g * 32768);
    unsigned short* pw = (unsigned short*)(smem + 131072 + w * 2304);
    float* mOp = (float*)(smem) + wq * 2048;            // 16x128 f32 per pair
    float* mml = (float*)(smem + 32768) + wq * 32;      // [2][16] per pair

    const unsigned short* Kbase = &K[(size_t)b * NT * ND];
    const unsigned short* Vbase = &Vt[(size_t)b * ND * NT];

    auto stage = [&](int buf, int s0) {
#pragma unroll
        for (int r = 0; r < 4; ++r) {          // K tile: 64 rows x 256B
            int off = r * 4096 + wq * 1024 + lane * 16;
            int row = off >> 8;
            int gcol = (off & 255) ^ ((row & 7) << 4);
            const unsigned short* src = Kbase + (size_t)(s0 + row) * ND + (gcol >> 1);
            __builtin_amdgcn_global_load_lds(
                (const __attribute__((address_space(1))) void*)src,
                (__attribute__((address_space(3))) void*)(Kg + ((buf * 16384 + r * 4096 + wq * 1024) >> 1)),
                16, 0, 0);
        }
#pragma unroll
        for (int r = 0; r < 4; ++r) {          // V tile: 128 rows x 128B
            int off = r * 4096 + wq * 1024 + lane * 16;
            int row = off >> 7;
            int gcol = (off & 127) ^ ((row & 7) << 4);
            const unsigned short* src = Vbase + (size_t)row * NT + s0 + (gcol >> 1);
            __builtin_amdgcn_global_load_lds(
                (const __attribute__((address_space(1))) void*)src,
                (__attribute__((address_space(3))) void*)(Vg + ((buf * 16384 + r * 4096 + wq * 1024) >> 1)),
                16, 0, 0);
        }
    };

    for (int half = 0; half < 2; ++half) {
        const int qt = half ? (63 - p) : p;
        const int qb0 = qt * 64;
        const int qw0 = qb0 + wq * 16;
        const int niter = (qt + 2) >> 1;       // ceil((qt+1)/2)

        short8 qf[4];
        const size_t qbase = ((size_t)b * NT + qw0 + l15) * ND;
#pragma unroll
        for (int c = 0; c < 4; ++c)
            qf[c] = *reinterpret_cast<const short8*>(&Q[qbase + c * 32 + lg * 8]);

        f32x4 o[8];
#pragma unroll
        for (int jn = 0; jn < 8; ++jn) o[jn] = (f32x4)0.0f;
        float mrow[4], lsum[4];
#pragma unroll
        for (int r = 0; r < 4; ++r) { mrow[r] = -1e30f; lsum[r] = 0.0f; }

        if (g <= qt) stage(0, g * 64);
        __syncthreads();                       // drains vmcnt: first tiles ready
        int cur = 0;

        for (int i = 0; i < niter; ++i) {
            const int t = 2 * i + g;
            const int s0 = t * 64;
            if (t + 2 <= qt) stage(cur ^ 1, (t + 2) * 64);

            if (t <= qt) {
                // ---- S = Q K^T from Kg[cur] ----
                const unsigned short* KlC = Kg + cur * 8192;
                f32x4 s[4];
#pragma unroll
                for (int j = 0; j < 4; ++j) s[j] = (f32x4)0.0f;
                __builtin_amdgcn_s_setprio(1);
#pragma unroll
                for (int j = 0; j < 4; ++j) {
                    const int row = j * 16 + l15;
                    const int cb = (row & 7) << 4;
#pragma unroll
                    for (int c = 0; c < 4; ++c) {
                        short8 kf = *reinterpret_cast<const short8*>(
                            &KlC[row * 128 + (((c * 64 + lg * 16) ^ cb) >> 1)]);
                        s[j] = __builtin_amdgcn_mfma_f32_16x16x32_bf16(qf[c], kf, s[j], 0, 0, 0);
                    }
                }
                __builtin_amdgcn_s_setprio(0);

                // ---- prefetch V half (jn=0..3) from LDS ----
                const unsigned short* VlC = Vg + cur * 8192;
                short8 vf0[8];
#pragma unroll
                for (int jn = 0; jn < 4; ++jn) {
                    const int row = jn * 16 + l15;
                    const int cb = (row & 7) << 4;
#pragma unroll
                    for (int kc = 0; kc < 2; ++kc)
                        vf0[jn * 2 + kc] = *reinterpret_cast<const short8*>(
                            &VlC[row * 64 + (((kc * 64 + lg * 16) ^ cb) >> 1)]);
                }

                // ---- softmax (online) ----
                const bool diag = (s0 + 64 > qw0);
                float tmax[4];
#pragma unroll
                for (int r = 0; r < 4; ++r) tmax[r] = -1e30f;
#pragma unroll
                for (int j = 0; j < 4; ++j)
#pragma unroll
                    for (int r = 0; r < 4; ++r) {
                        float sv = s[j][r] * sc;
                        if (diag) {
                            int qrow = qw0 + lg * 4 + r;
                            int scol = s0 + j * 16 + l15;
                            if (scol > qrow) sv = -1e30f;
                        }
                        s[j][r] = sv;
                        tmax[r] = fmaxf(tmax[r], sv);
                    }
#pragma unroll
                for (int r = 0; r < 4; ++r) {
#pragma unroll
                    for (int off = 1; off < 16; off <<= 1)
                        tmax[r] = fmaxf(tmax[r], __shfl_xor(tmax[r], off, 64));
                }
                float alpha[4], psum[4];
#pragma unroll
                for (int r = 0; r < 4; ++r) {
                    float mn = fmaxf(mrow[r], tmax[r]);
                    alpha[r] = exp2f((mrow[r] - mn) * L2E);
                    mrow[r] = mn;
                    psum[r] = 0.0f;
                }
#pragma unroll
                for (int j = 0; j < 4; ++j)
#pragma unroll
                    for (int r = 0; r < 4; ++r) {
                        float pv = exp2f((s[j][r] - mrow[r]) * L2E);
                        s[j][r] = pv;
                        psum[r] += pv;
                    }
#pragma unroll
                for (int r = 0; r < 4; ++r) {
#pragma unroll
                    for (int off = 1; off < 16; off <<= 1)
                        psum[r] += __shfl_xor(psum[r], off, 64);
                    lsum[r] = lsum[r] * alpha[r] + psum[r];
                }
#pragma unroll
                for (int jn = 0; jn < 8; ++jn)
#pragma unroll
                    for (int r = 0; r < 4; ++r) o[jn][r] *= alpha[r];

                // ---- P -> LDS (D-layout coords), reload as A-frags ----
#pragma unroll
                for (int j = 0; j < 4; ++j)
#pragma unroll
                    for (int r = 0; r < 4; ++r)
                        pw[(lg * 4 + r) * 72 + j * 16 + l15] = f2bf(s[j][r]);
                asm volatile("s_waitcnt lgkmcnt(0)" ::: "memory");
                short8 pa[2];
#pragma unroll
                for (int kc = 0; kc < 2; ++kc)
                    pa[kc] = *reinterpret_cast<const short8*>(&pw[l15 * 72 + kc * 32 + lg * 8]);

                // ---- O += P V ----
                __builtin_amdgcn_s_setprio(1);
#pragma unroll
                for (int jn = 0; jn < 4; ++jn)
#pragma unroll
                    for (int kc = 0; kc < 2; ++kc)
                        o[jn] = __builtin_amdgcn_mfma_f32_16x16x32_bf16(
                            pa[kc], vf0[jn * 2 + kc], o[jn], 0, 0, 0);
#pragma unroll
                for (int jn = 4; jn < 8; ++jn) {
                    const int row = jn * 16 + l15;
                    const int cb = (row & 7) << 4;
#pragma unroll
                    for (int kc = 0; kc < 2; ++kc) {
                        short8 vf = *reinterpret_cast<const short8*>(
                            &VlC[row * 64 + (((kc * 64 + lg * 16) ^ cb) >> 1)]);
                        o[jn] = __builtin_amdgcn_mfma_f32_16x16x32_bf16(pa[kc], vf, o[jn], 0, 0, 0);
                    }
                }
                __builtin_amdgcn_s_setprio(0);
            }

            __syncthreads();                   // prefetch done + reads drained
            cur ^= 1;
        }

        // ---- merge: group1 publishes (m,l,O) via LDS (aliases dead K region) ----
        if (g == 1) {
#pragma unroll
            for (int jn = 0; jn < 8; ++jn)
#pragma unroll
                for (int r = 0; r < 4; ++r)
                    mOp[(lg * 4 + r) * 128 + jn * 16 + l15] = o[jn][r];
            if (l15 == 0) {
#pragma unroll
                for (int r = 0; r < 4; ++r) {
                    mml[lg * 4 + r] = mrow[r];
                    mml[16 + lg * 4 + r] = lsum[r];
                }
            }
        }
        __syncthreads();
        if (g == 0) {
            float e0[4], e1[4], rL[4];
#pragma unroll
            for (int r = 0; r < 4; ++r) {
                int rr = lg * 4 + r;
                float m1 = mml[rr], l1 = mml[16 + rr];
                float M = fmaxf(mrow[r], m1);
                e0[r] = exp2f((mrow[r] - M) * L2E);
                e1[r] = exp2f((m1 - M) * L2E);
                rL[r] = 1.0f / (lsum[r] * e0[r] + l1 * e1[r]);
            }
#pragma unroll
            for (int jn = 0; jn < 8; ++jn)
#pragma unroll
                for (int r = 0; r < 4; ++r) {
                    int rr = lg * 4 + r, cc = jn * 16 + l15;
                    float v = o[jn][r] * e0[r] + mOp[rr * 128 + cc] * e1[r];
                    out[((size_t)b * NT + qw0 + rr) * ND + cc] = v * rL[r];
                }
        }
        __syncthreads();                       // merge reads done before restaging
    }
}

extern "C" void kernel_launch(void* const* d_in, const int* in_sizes, int n_in,
                              void* d_out, int out_size, void* d_ws, size_t ws_size,
                              hipStream_t stream) {
    const float* x  = (const float*)d_in[0];
    const float* Wq = (const float*)d_in[1];
    const float* Wk = (const float*)d_in[2];
    const float* Wv = (const float*)d_in[3];
    float* out = (float*)d_out;

    unsigned short* ws  = (unsigned short*)d_ws;
    unsigned short* Wbt = ws;                               // 3*128*1024
    unsigned short* Qb  = Wbt + 3 * ND * NC;                // 8*4096*128
    unsigned short* Kb  = Qb + (size_t)NB * NT * ND;
    unsigned short* Vtb = Kb + (size_t)NB * NT * ND;        // transposed [B][D][T]

    prep_w<<<1536, 256, 0, stream>>>(Wq, Wk, Wv, Wbt);
    qkv_gemm<<<dim3(256, 3), 256, 0, stream>>>(x, Wbt, Qb, Kb, Vtb);
    attn_fwd<<<256, 512, 0, stream>>>(Qb, Kb, Vtb, out);
}